// Round 1
// 125.581 us; speedup vs baseline: 1.0103x; 1.0103x over previous
//
#include <hip/hip_runtime.h>
#include <hip/hip_bf16.h>

#define Bsz 4
#define Lsz 2048
#define Hsz 8

typedef __attribute__((ext_vector_type(8))) short bf16x8;
typedef __attribute__((ext_vector_type(4))) short bf16x4;
typedef __attribute__((ext_vector_type(4))) float f32x4;

__device__ __forceinline__ short f2bs(float f) {   // RNE, prep only
    union { float f; unsigned u; } v; v.f = f;
    unsigned r = v.u + 0x7FFFu + ((v.u >> 16) & 1u);
    return (short)(r >> 16);
}
__device__ __forceinline__ short f2bs_rh(float f) { // round-half-up, 2 ops
    return (short)((__float_as_uint(f) + 0x8000u) >> 16);
}

// async global->LDS, 16B per lane; LDS dest is wave-uniform base + lane*16
__device__ __forceinline__ void stage16(const short* g, short* l) {
    __builtin_amdgcn_global_load_lds(
        (const __attribute__((address_space(1))) unsigned int*)g,
        (__attribute__((address_space(3))) unsigned int*)l,
        16, 0, 0);
}

// ---------------- fused pre-pass: K and V -> bf16 MFMA fragments ----------------
// (unchanged from previous round — near BW floor)
__global__ __launch_bounds__(256) void prep_kv(
    const float* __restrict__ ksrc, const float* __restrict__ vsrc,
    short* __restrict__ Kf, short* __restrict__ Vf)
{
    __shared__ float Tl[64][65];
    const int raw = blockIdx.x;
    const int tid = threadIdx.x;
    const bool isK = raw < Bsz*Hsz*32;
    const int bid = isK ? raw : raw - Bsz*Hsz*32;
    const int tl = bid & 31, bh = bid >> 5;
    const int b = bh >> 3, h = bh & 7;

    const int row = tid >> 2, c0 = (tid & 3) * 16;
    const float* src = (isK ? ksrc : vsrc)
                     + (((size_t)b*Lsz + tl*64 + row)*Hsz + h)*64 + c0;
    *(float4*)&Tl[row][c0]      = *(const float4*)(src);
    *(float4*)&Tl[row][c0 + 4]  = *(const float4*)(src + 4);
    *(float4*)&Tl[row][c0 + 8]  = *(const float4*)(src + 8);
    *(float4*)&Tl[row][c0 + 12] = *(const float4*)(src + 12);
    __syncthreads();

    const int lane = tid & 63, ln = lane & 15, quad = lane >> 4;
    if (isK) {
        short* dst = Kf + (size_t)bid * 4096;
        #pragma unroll
        for (int cc = 0; cc < 2; ++cc) {
            const int c  = (tid >> 6)*2 + cc;
            const int nt = c >> 1, eh = c & 1;
            const float* rp = &Tl[nt*16 + ln][eh*32 + quad*8];
            bf16x8 o = {f2bs(rp[0]),f2bs(rp[1]),f2bs(rp[2]),f2bs(rp[3]),
                        f2bs(rp[4]),f2bs(rp[5]),f2bs(rp[6]),f2bs(rp[7])};
            *(bf16x8*)(dst + c*512 + lane*8) = o;
        }
    } else {
        short* dst = Vf + (size_t)bid * 4096;
        #pragma unroll
        for (int cc = 0; cc < 2; ++cc) {
            const int cp  = (tid >> 6)*2 + cc;
            const int m16 = cp >> 1, nt0 = (cp & 1)*2;
            const int d   = m16*16 + ln;
            const int s0  = nt0*16 + quad*4;
            bf16x8 o = {f2bs(Tl[s0+0][d]),  f2bs(Tl[s0+1][d]),
                        f2bs(Tl[s0+2][d]),  f2bs(Tl[s0+3][d]),
                        f2bs(Tl[s0+16][d]), f2bs(Tl[s0+17][d]),
                        f2bs(Tl[s0+18][d]), f2bs(Tl[s0+19][d])};
            *(bf16x8*)(dst + cp*512 + lane*8) = o;
        }
    }
}

// ---------------- main: S^T flash attention, SOFTWARE-PIPELINED ----------------
// body(t): stage(t+1) | QK(t)->bankW | SM(t-1) on bankR (VALU overlaps in-flight
// QK MFMAs) | PV(t-1) from V-regs | V(t)->regs | barrier.
// Banks are compile-time (macro unroll-by-2) to keep everything in VGPRs.
// Diagonal-mask tile (t==qt==T-1) lives entirely in the epilogue -> maskless loop.
__global__ __launch_bounds__(256, 4) void dsattn_main(
    const float* __restrict__ q,
    const short* __restrict__ Kf,
    const short* __restrict__ Vf,
    const float* __restrict__ tau,
    const float* __restrict__ delta,
    float* __restrict__ out)
{
    __shared__ __align__(16) short Kb[2][4096];   // 16 KB dbuf
    __shared__ __align__(16) short Vb[2][4096];   // 16 KB dbuf
    __shared__ float dls[Lsz];                    //  8 KB c2*delta[b][:]
    // total 40 KB -> 4 blocks/CU = 160 KB = full LDS

    const int tid  = threadIdx.x;
    const int wv   = tid >> 6;
    const int lane = tid & 63;
    const int ln   = lane & 15;
    const int quad = lane >> 4;

    const int bh = blockIdx.x;
    const int b  = bh >> 3, h = bh & 7;
    // co-resident y-group {y0, y0+8, y0+16, y0+24} -> qt {a,15-a,16+a,31-a}:
    // per-CU tile total = 66, balanced
    const int j  = blockIdx.y, aj = j & 7, gj = j >> 3;
    const int qt = (gj == 0) ? aj : (gj == 1) ? 15 - aj
                 : (gj == 2) ? 16 + aj : 31 - aj;
    const int q0 = qt * 64;
    const int T  = qt + 1;              // 64-key tiles

    const float c2  = 0.125f * 1.44269504f;   // scale * log2(e)
    const float st2 = c2 * tau[b];

    const short* kt = Kf + (size_t)bh * (32*4096);
    const short* vt = Vf + (size_t)bh * (32*4096);

    // one incremental staging pointer per wave: waves 0,1 -> K chunks, 2,3 -> V
    const short* gsrc = ((wv < 2) ? kt : vt) + (wv & 1)*2048 + lane*8;

#define STAGE(buf) do {                                                     \
        short* lb_ = (wv < 2 ? &Kb[(buf)][0] : &Vb[(buf)][0]) + (wv&1)*2048;\
        stage16(gsrc + 0*512, lb_ + 0*512);                                 \
        stage16(gsrc + 1*512, lb_ + 1*512);                                 \
        stage16(gsrc + 2*512, lb_ + 2*512);                                 \
        stage16(gsrc + 3*512, lb_ + 3*512);                                 \
        gsrc += 4096;                                                       \
    } while (0)

    // stage tile 0 first (longest latency), then dls, then Q frags
    STAGE(0);

    {
        const float* dsrc = delta + (size_t)b*Lsz + tid*8;
        float4 a = *(const float4*)(dsrc);
        float4 c = *(const float4*)(dsrc + 4);
        a.x*=c2; a.y*=c2; a.z*=c2; a.w*=c2;
        c.x*=c2; c.y*=c2; c.z*=c2; c.w*=c2;
        *(float4*)&dls[tid*8]     = a;
        *(float4*)&dls[tid*8 + 4] = c;
    }

    // Q fragments (B-operand of 16x16x32), straight from fp32 global
    bf16x8 qf0, qf1;
    {
        const float* qrow = q + (((size_t)b*Lsz + q0 + wv*16 + ln)*Hsz + h)*64;
        float4 a0 = *(const float4*)(qrow + quad*8);
        float4 a1 = *(const float4*)(qrow + quad*8 + 4);
        float4 b0 = *(const float4*)(qrow + 32 + quad*8);
        float4 b1 = *(const float4*)(qrow + 32 + quad*8 + 4);
        qf0 = (bf16x8){f2bs(a0.x),f2bs(a0.y),f2bs(a0.z),f2bs(a0.w),
                       f2bs(a1.x),f2bs(a1.y),f2bs(a1.z),f2bs(a1.w)};
        qf1 = (bf16x8){f2bs(b0.x),f2bs(b0.y),f2bs(b0.z),f2bs(b0.w),
                       f2bs(b1.x),f2bs(b1.y),f2bs(b1.z),f2bs(b1.w)};
    }

    f32x4 oacc[4];
    #pragma unroll
    for (int m = 0; m < 4; ++m) oacc[m] = (f32x4){0.f,0.f,0.f,0.f};
    f32x4 sE[4], sO[4];          // two compile-time sacc banks
    bf16x8 vv[8];                // V(t) register tile (single bank)
    bf16x4 pT[4];
    float l_acc = 0.f;

#define QK(tt, SW) do {                                                     \
        const short* Kc_ = &Kb[(tt)&1][0];                                  \
        _Pragma("unroll")                                                   \
        for (int nt = 0; nt < 4; ++nt) {                                    \
            bf16x8 kf0_ = *(const bf16x8*)(Kc_ + (nt*2+0)*512 + lane*8);    \
            bf16x8 kf1_ = *(const bf16x8*)(Kc_ + (nt*2+1)*512 + lane*8);    \
            f32x4 z_ = (f32x4){0.f,0.f,0.f,0.f};                            \
            z_ = __builtin_amdgcn_mfma_f32_16x16x32_bf16(kf0_, qf0, z_, 0,0,0); \
            (SW)[nt] = __builtin_amdgcn_mfma_f32_16x16x32_bf16(kf1_, qf1, z_, 0,0,0); \
        }                                                                   \
    } while (0)

#define SM(tm, SR) do {                                                     \
        const int k0_ = (tm)*64;                                            \
        _Pragma("unroll")                                                   \
        for (int nt = 0; nt < 4; ++nt) {                                    \
            f32x4 dlv_ = *(const f32x4*)&dls[k0_ + nt*16 + quad*4];         \
            float p0_ = __builtin_amdgcn_exp2f(fmaf((SR)[nt][0], st2, dlv_[0])); \
            float p1_ = __builtin_amdgcn_exp2f(fmaf((SR)[nt][1], st2, dlv_[1])); \
            float p2_ = __builtin_amdgcn_exp2f(fmaf((SR)[nt][2], st2, dlv_[2])); \
            float p3_ = __builtin_amdgcn_exp2f(fmaf((SR)[nt][3], st2, dlv_[3])); \
            l_acc += (p0_ + p1_) + (p2_ + p3_);                             \
            pT[nt] = (bf16x4){f2bs_rh(p0_), f2bs_rh(p1_),                   \
                              f2bs_rh(p2_), f2bs_rh(p3_)};                  \
        }                                                                   \
    } while (0)

#define PV() do {                                                           \
        _Pragma("unroll")                                                   \
        for (int ntp = 0; ntp < 2; ++ntp)                                   \
            _Pragma("unroll")                                               \
            for (int m16 = 0; m16 < 4; ++m16) {                             \
                bf16x8 v8_ = vv[m16*2 + ntp];                               \
                bf16x4 v0_ = (bf16x4){v8_[0], v8_[1], v8_[2], v8_[3]};      \
                bf16x4 v1_ = (bf16x4){v8_[4], v8_[5], v8_[6], v8_[7]};      \
                oacc[m16] = __builtin_amdgcn_mfma_f32_16x16x16bf16_1k(      \
                    v0_, pT[2*ntp+0], oacc[m16], 0,0,0);                    \
                oacc[m16] = __builtin_amdgcn_mfma_f32_16x16x16bf16_1k(      \
                    v1_, pT[2*ntp+1], oacc[m16], 0,0,0);                    \
            }                                                               \
    } while (0)

#define VLOAD(tt) do {                                                      \
        const short* Vc_ = &Vb[(tt)&1][0];                                  \
        _Pragma("unroll")                                                   \
        for (int c = 0; c < 8; ++c)                                         \
            vv[c] = *(const bf16x8*)(Vc_ + c*512 + lane*8);                 \
    } while (0)

#define BODY(tt, SW, SR) do {                                               \
        if ((tt) + 1 < T) STAGE(((tt)+1)&1);                                \
        __builtin_amdgcn_s_setprio(1);                                      \
        QK((tt), SW);            /* MFMA burst, fills pipe          */      \
        SM((tt)-1, SR);          /* VALU, independent -> overlaps   */      \
        PV();                    /* MFMA burst on previous tile     */      \
        __builtin_amdgcn_s_setprio(0);                                      \
        VLOAD(tt);               /* V(t) -> regs for next body      */      \
        __syncthreads();                                                    \
    } while (0)

    __syncthreads();             // tile 0 + dls staged

    // ---- prologue = body(0) without SM/PV ----
    if (T > 1) STAGE(1);
    __builtin_amdgcn_s_setprio(1);
    QK(0, sE);
    __builtin_amdgcn_s_setprio(0);
    VLOAD(0);
    __syncthreads();             // tile 1 staged; all waves done with buf 0

    // ---- pipelined main loop, banks alternate at compile time ----
    int t = 1;
    for (; t + 1 < T; t += 2) {
        BODY(t,     sO, sE);
        BODY(t + 1, sE, sO);
    }
    if (t < T) BODY(t, sO, sE);

    if ((T - 1) & 1) {           // normalize final bank -> sE
        #pragma unroll
        for (int nt = 0; nt < 4; ++nt) sE[nt] = sO[nt];
    }

    // ---- epilogue: diagonal tile T-1 (the only masked one) ----
    {
        const int k0 = (T - 1) * 64;
        const int qrow = q0 + wv*16 + ln;
        #pragma unroll
        for (int nt = 0; nt < 4; ++nt)
            #pragma unroll
            for (int r = 0; r < 4; ++r)
                if (k0 + nt*16 + quad*4 + r > qrow) sE[nt][r] = -1e30f;
        SM(T - 1, sE);
        PV();
    }

    // ---- reduce l across quads, normalize, store O (fp32) ----
    float lsum = l_acc;
    lsum += __shfl_xor(lsum, 16, 64);
    lsum += __shfl_xor(lsum, 32, 64);
    const float inv = 1.0f / lsum;
    const int qrow = q0 + wv*16 + ln;
    float* orow = out + (((size_t)b*Lsz + qrow)*Hsz + h)*64;
    #pragma unroll
    for (int m16 = 0; m16 < 4; ++m16) {
        float4 o = {oacc[m16][0]*inv, oacc[m16][1]*inv,
                    oacc[m16][2]*inv, oacc[m16][3]*inv};
        *(float4*)(orow + m16*16 + quad*4) = o;
    }
#undef STAGE
#undef QK
#undef SM
#undef PV
#undef VLOAD
#undef BODY
}

extern "C" void kernel_launch(void* const* d_in, const int* in_sizes, int n_in,
                              void* d_out, int out_size, void* d_ws, size_t ws_size,
                              hipStream_t stream) {
    (void)in_sizes; (void)n_in; (void)out_size; (void)ws_size;
    const float* q     = (const float*)d_in[0];
    const float* k     = (const float*)d_in[1];
    const float* v     = (const float*)d_in[2];
    const float* tau   = (const float*)d_in[3];
    const float* delta = (const float*)d_in[4];
    float* out = (float*)d_out;

    short* Kf = (short*)d_ws;                          // 8 MiB bf16 fragments
    short* Vf = (short*)d_ws + (size_t)(4*1024*1024);  // next 8 MiB

    prep_kv<<<dim3(Bsz*Hsz*32*2), dim3(256), 0, stream>>>(k, v, Kf, Vf);
    dsattn_main<<<dim3(Bsz*Hsz, 32), dim3(256), 0, stream>>>(q, Kf, Vf, tau, delta, out);
}

// Round 2
// 123.911 us; speedup vs baseline: 1.0239x; 1.0135x over previous
//
#include <hip/hip_runtime.h>
#include <hip/hip_bf16.h>

#define Bsz 4
#define Lsz 2048
#define Hsz 8

typedef __attribute__((ext_vector_type(8)))  short bf16x8;
typedef __attribute__((ext_vector_type(4)))  float f32x4;
typedef __attribute__((ext_vector_type(16))) float f32x16;
typedef __attribute__((ext_vector_type(2)))  unsigned u32x2;

__device__ __forceinline__ short f2bs(float f) {   // RNE, prep/Q only
    union { float f; unsigned u; } v; v.f = f;
    unsigned r = v.u + 0x7FFFu + ((v.u >> 16) & 1u);
    return (short)(r >> 16);
}
__device__ __forceinline__ unsigned cvtpk(float lo, float hi) {
    unsigned r;
    asm("v_cvt_pk_bf16_f32 %0, %1, %2" : "=v"(r) : "v"(lo), "v"(hi));
    return r;
}

// async global->LDS, 16B per lane; LDS dest is wave-uniform base + lane*16
__device__ __forceinline__ void stage16(const short* g, short* l) {
    __builtin_amdgcn_global_load_lds(
        (const __attribute__((address_space(1))) unsigned int*)g,
        (__attribute__((address_space(3))) unsigned int*)l,
        16, 0, 0);
}

// ---------------- pre-pass: K and V -> bf16 32x32x16 MFMA fragments ----------------
// Per (bh, 64-key tile): 8 chunks x 1024 B each for K and V, frag position = lane.
// K chunk c=kh*4+eb, lane(l31,hi):  K[kh*32+l31][eb*16+hi*8+j]        (A-op 32x32x16)
// V chunk c=dh*4+kb, lane(l31,hi):  V[kb*16+hi*8+j][dh*32+l31]  (V^T)  (A-op 32x32x16)
__global__ __launch_bounds__(256) void prep_kv(
    const float* __restrict__ ksrc, const float* __restrict__ vsrc,
    short* __restrict__ Kf, short* __restrict__ Vf)
{
    __shared__ float Tl[64][65];
    const int raw = blockIdx.x;
    const int tid = threadIdx.x;
    const bool isK = raw < Bsz*Hsz*32;
    const int bid = isK ? raw : raw - Bsz*Hsz*32;
    const int tl = bid & 31, bh = bid >> 5;
    const int b = bh >> 3, h = bh & 7;

    // coalesced stage of the 64x64 fp32 tile
    const int row = tid >> 2, c0 = (tid & 3) * 16;
    const float* src = (isK ? ksrc : vsrc)
                     + (((size_t)b*Lsz + tl*64 + row)*Hsz + h)*64 + c0;
    *(float4*)&Tl[row][c0]      = *(const float4*)(src);
    *(float4*)&Tl[row][c0 + 4]  = *(const float4*)(src + 4);
    *(float4*)&Tl[row][c0 + 8]  = *(const float4*)(src + 8);
    *(float4*)&Tl[row][c0 + 12] = *(const float4*)(src + 12);
    __syncthreads();

    const int lane = tid & 63, l31 = lane & 31, hi = lane >> 5;
    if (isK) {
        short* dst = Kf + (size_t)bid * 4096;
        #pragma unroll
        for (int cc = 0; cc < 2; ++cc) {
            const int c  = (tid >> 6)*2 + cc;      // 0..7
            const int kh = c >> 2, eb = c & 3;
            const float* rp = &Tl[kh*32 + l31][eb*16 + hi*8];
            bf16x8 o = {f2bs(rp[0]),f2bs(rp[1]),f2bs(rp[2]),f2bs(rp[3]),
                        f2bs(rp[4]),f2bs(rp[5]),f2bs(rp[6]),f2bs(rp[7])};
            *(bf16x8*)(dst + c*512 + lane*8) = o;
        }
    } else {
        short* dst = Vf + (size_t)bid * 4096;
        #pragma unroll
        for (int cc = 0; cc < 2; ++cc) {
            const int c  = (tid >> 6)*2 + cc;      // 0..7
            const int dh = c >> 2, kb = c & 3;
            const int d  = dh*32 + l31;
            const int s0 = kb*16 + hi*8;
            bf16x8 o = {f2bs(Tl[s0+0][d]), f2bs(Tl[s0+1][d]),
                        f2bs(Tl[s0+2][d]), f2bs(Tl[s0+3][d]),
                        f2bs(Tl[s0+4][d]), f2bs(Tl[s0+5][d]),
                        f2bs(Tl[s0+6][d]), f2bs(Tl[s0+7][d])};
            *(bf16x8*)(dst + c*512 + lane*8) = o;
        }
    }
}

// ---------------- main: S^T flash attention, 32x32x16 MFMA, 2x2 wave split ---------
// 4 waves: wave (kh=wv>>1, qh=wv&1) owns keys kh*32..+32, q-rows qh*32..+32 of the
// 64x64 tile. Each wave reads only HALF of K and HALF of V from LDS (32 KB/tile/block
// vs 64 before), runs 4+4 full-rate 32x32x16 MFMAs (vs 8+16 with half-rate PV).
// P^T repack to B-operand via cvt_pk_bf16 + permlane32_swap (T12 / HK pattern).
// O accumulates per k-half; one LDS cross-wave (kh) reduction at the epilogue.
__global__ __launch_bounds__(256, 4) void dsattn_main(
    const float* __restrict__ q,
    const short* __restrict__ Kf,
    const short* __restrict__ Vf,
    const float* __restrict__ tau,
    const float* __restrict__ delta,
    float* __restrict__ out)
{
    __shared__ __align__(16) short Kb[2][4096];   // 16 KB dbuf (reused as Ored)
    __shared__ __align__(16) short Vb[2][4096];   // 16 KB dbuf (reused as lred)
    __shared__ float dls[Lsz];                    //  8 KB c2*delta[b][:]
    // total 40 KB -> 4 blocks/CU = 160 KB = full LDS

    const int tid  = threadIdx.x;
    const int wv   = tid >> 6;
    const int lane = tid & 63;
    const int l31  = lane & 31;
    const int hi   = lane >> 5;
    const int qh   = wv & 1;          // q-half of the 64-row block
    const int kh   = wv >> 1;         // key-half of each 64-key tile

    const int bh = blockIdx.x;
    const int b  = bh >> 3, h = bh & 7;
    // co-resident y-group {y0,y0+8,y0+16,y0+24} -> qt {31-2a,30-2a,2a+1,2a}:
    // per-CU total = 66 AND the two long blocks retire together (tail fix)
    const int j  = blockIdx.y, aj = j & 7, gj = j >> 3;
    const int qt = (gj == 0) ? 31 - 2*aj : (gj == 1) ? 30 - 2*aj
                 : (gj == 2) ? 2*aj + 1  : 2*aj;
    const int q0 = qt * 64;
    const int T  = qt + 1;            // 64-key tiles

    const float c2  = 0.125f * 1.44269504f;   // scale * log2(e)
    const float st2 = c2 * tau[b];

    const short* kt = Kf + (size_t)bh * (32*4096);
    const short* vt = Vf + (size_t)bh * (32*4096);

    // incremental staging pointer: waves 0,1 -> K chunks, 2,3 -> V chunks
    const short* gsrc = ((wv < 2) ? kt : vt) + (wv & 1)*2048 + lane*8;

#define STAGE(buf) do {                                                     \
        short* lb_ = (wv < 2 ? &Kb[(buf)][0] : &Vb[(buf)][0]) + (wv&1)*2048;\
        stage16(gsrc + 0*512, lb_ + 0*512);                                 \
        stage16(gsrc + 1*512, lb_ + 1*512);                                 \
        stage16(gsrc + 2*512, lb_ + 2*512);                                 \
        stage16(gsrc + 3*512, lb_ + 3*512);                                 \
        gsrc += 4096;                                                       \
    } while (0)

    STAGE(0);                         // tile 0 in flight first

    // stage c2*delta (256 thr x 8 floats)
    {
        const float* dsrc = delta + (size_t)b*Lsz + tid*8;
        float4 a = *(const float4*)(dsrc);
        float4 c = *(const float4*)(dsrc + 4);
        a.x*=c2; a.y*=c2; a.z*=c2; a.w*=c2;
        c.x*=c2; c.y*=c2; c.z*=c2; c.w*=c2;
        *(float4*)&dls[tid*8]     = a;
        *(float4*)&dls[tid*8 + 4] = c;
    }

    // Q fragments: B-operand 32x32x16 per 16-e block:
    // lane holds Q[q0+qh*32+l31][eb*16 + hi*8 + j], j=0..7
    bf16x8 qf[4];
    {
        const float* qrow = q + (((size_t)b*Lsz + q0 + qh*32 + l31)*Hsz + h)*64 + hi*8;
        #pragma unroll
        for (int eb = 0; eb < 4; ++eb) {
            float4 a0 = *(const float4*)(qrow + eb*16);
            float4 a1 = *(const float4*)(qrow + eb*16 + 4);
            qf[eb] = (bf16x8){f2bs(a0.x),f2bs(a0.y),f2bs(a0.z),f2bs(a0.w),
                              f2bs(a1.x),f2bs(a1.y),f2bs(a1.z),f2bs(a1.w)};
        }
    }

    f32x16 oacc0, oacc1;              // O^T partials: d 0..31 / 32..63, this k-half
    #pragma unroll
    for (int i = 0; i < 16; ++i) { oacc0[i] = 0.f; oacc1[i] = 0.f; }
    float l_acc = 0.f;

    __syncthreads();                  // tile 0 + dls staged (barrier drains vmcnt)

    // one tile body; MASKED folds at compile time via literal call sites
#define TILE_BODY(t_, MASKED) do {                                          \
        const int cur_ = (t_) & 1;                                          \
        const short* Kc_ = &Kb[cur_][0];                                    \
        const short* Vc_ = &Vb[cur_][0];                                    \
        const int k0_ = (t_)*64;                                            \
        /* S^T = K Q^T : C row = key_loc = (r&3)+8*(r>>2)+4*hi, col = q = l31 */ \
        f32x16 sacc;                                                        \
        _Pragma("unroll")                                                   \
        for (int i = 0; i < 16; ++i) sacc[i] = 0.f;                         \
        __builtin_amdgcn_s_setprio(1);                                      \
        _Pragma("unroll")                                                   \
        for (int eb = 0; eb < 4; ++eb) {                                    \
            bf16x8 kf_ = *(const bf16x8*)(Kc_ + (kh*4 + eb)*512 + lane*8);  \
            sacc = __builtin_amdgcn_mfma_f32_32x32x16_bf16(kf_, qf[eb], sacc, 0,0,0); \
        }                                                                   \
        __builtin_amdgcn_s_setprio(0);                                      \
        if (MASKED) {                                                       \
            const int qrw_ = qh*32 + l31;                                   \
            _Pragma("unroll")                                               \
            for (int g = 0; g < 4; ++g)                                     \
                _Pragma("unroll")                                           \
                for (int i = 0; i < 4; ++i)                                 \
                    if (kh*32 + 8*g + 4*hi + i > qrw_) sacc[g*4+i] = -1e30f;\
        }                                                                   \
        /* softmax numerator + row-sum */                                   \
        float p_[16];                                                       \
        _Pragma("unroll")                                                   \
        for (int g = 0; g < 4; ++g) {                                       \
            f32x4 dlv_ = *(const f32x4*)&dls[k0_ + kh*32 + g*8 + hi*4];     \
            _Pragma("unroll")                                               \
            for (int i = 0; i < 4; ++i)                                     \
                p_[g*4+i] = __builtin_amdgcn_exp2f(fmaf(sacc[g*4+i], st2, dlv_[i])); \
            l_acc += (p_[g*4]+p_[g*4+1]) + (p_[g*4+2]+p_[g*4+3]);           \
        }                                                                   \
        /* P^T -> B-operand frags: cvt_pk + permlane32_swap (T12) */        \
        bf16x8 pf_[2];                                                      \
        _Pragma("unroll")                                                   \
        for (int kb = 0; kb < 2; ++kb) {                                    \
            unsigned a0_ = cvtpk(p_[kb*8+0], p_[kb*8+1]);                   \
            unsigned a1_ = cvtpk(p_[kb*8+2], p_[kb*8+3]);                   \
            unsigned b0_ = cvtpk(p_[kb*8+4], p_[kb*8+5]);                   \
            unsigned b1_ = cvtpk(p_[kb*8+6], p_[kb*8+7]);                   \
            u32x2 s0_ = __builtin_amdgcn_permlane32_swap(a0_, b0_, false, false); \
            u32x2 s1_ = __builtin_amdgcn_permlane32_swap(a1_, b1_, false, false); \
            union { unsigned u[4]; bf16x8 v; } pk_;                         \
            pk_.u[0] = s0_[0]; pk_.u[1] = s1_[0];                           \
            pk_.u[2] = s0_[1]; pk_.u[3] = s1_[1];                           \
            pf_[kb] = pk_.v;                                                \
        }                                                                   \
        /* O^T += V^T P^T over this wave's 32 keys */                       \
        __builtin_amdgcn_s_setprio(1);                                      \
        _Pragma("unroll")                                                   \
        for (int kb = 0; kb < 2; ++kb) {                                    \
            bf16x8 vf0_ = *(const bf16x8*)(Vc_ + (     kh*2 + kb)*512 + lane*8); \
            bf16x8 vf1_ = *(const bf16x8*)(Vc_ + (4 +  kh*2 + kb)*512 + lane*8); \
            oacc0 = __builtin_amdgcn_mfma_f32_32x32x16_bf16(vf0_, pf_[kb], oacc0, 0,0,0); \
            oacc1 = __builtin_amdgcn_mfma_f32_32x32x16_bf16(vf1_, pf_[kb], oacc1, 0,0,0); \
        }                                                                   \
        __builtin_amdgcn_s_setprio(0);                                      \
    } while (0)

    // maskless main loop over tiles 0..T-2
    for (int t = 0; t + 1 < T; ++t) {
        STAGE((t + 1) & 1);           // stream tile t+1 into the other buffer
        TILE_BODY(t, false);
        __syncthreads();              // staged t+1 complete + all reads of cur done
    }
    // diagonal tile T-1 (the only masked one)
    TILE_BODY(T - 1, true);

    // ---- cross-wave (kh) reduction via LDS, then normalize + store ----
    float lw = l_acc + __shfl_xor(l_acc, 32, 64);   // hi-half fold, per q=l31
    float* Ored = (float*)&Kb[0][0];  // 2*64*32 f32 = 16 KB
    float* lred = (float*)&Vb[0][0];  // 64 f32
    __syncthreads();                  // everyone done with Kb/Vb tile data

    if (kh == 1) {
        #pragma unroll
        for (int g = 0; g < 4; ++g)
            #pragma unroll
            for (int i = 0; i < 4; ++i) {
                const int d_ = 8*g + 4*hi + i;
                Ored[(qh*64 +      d_)*32 + l31] = oacc0[g*4+i];
                Ored[(qh*64 + 32 + d_)*32 + l31] = oacc1[g*4+i];
            }
        if (lane < 32) lred[qh*32 + l31] = lw;
    }
    __syncthreads();

    if (kh == 0) {
        const float invl = 1.0f / (lw + lred[qh*32 + l31]);
        float* orow = out + (((size_t)b*Lsz + q0 + qh*32 + l31)*Hsz + h)*64;
        #pragma unroll
        for (int g = 0; g < 4; ++g) {
            const int d_ = 8*g + 4*hi;
            float4 o0, o1;
            o0.x = (oacc0[g*4+0] + Ored[(qh*64 + d_ + 0)*32 + l31]) * invl;
            o0.y = (oacc0[g*4+1] + Ored[(qh*64 + d_ + 1)*32 + l31]) * invl;
            o0.z = (oacc0[g*4+2] + Ored[(qh*64 + d_ + 2)*32 + l31]) * invl;
            o0.w = (oacc0[g*4+3] + Ored[(qh*64 + d_ + 3)*32 + l31]) * invl;
            o1.x = (oacc1[g*4+0] + Ored[(qh*64 + 32 + d_ + 0)*32 + l31]) * invl;
            o1.y = (oacc1[g*4+1] + Ored[(qh*64 + 32 + d_ + 1)*32 + l31]) * invl;
            o1.z = (oacc1[g*4+2] + Ored[(qh*64 + 32 + d_ + 2)*32 + l31]) * invl;
            o1.w = (oacc1[g*4+3] + Ored[(qh*64 + 32 + d_ + 3)*32 + l31]) * invl;
            *(float4*)(orow + d_)      = o0;
            *(float4*)(orow + 32 + d_) = o1;
        }
    }
#undef STAGE
#undef TILE_BODY
}

extern "C" void kernel_launch(void* const* d_in, const int* in_sizes, int n_in,
                              void* d_out, int out_size, void* d_ws, size_t ws_size,
                              hipStream_t stream) {
    (void)in_sizes; (void)n_in; (void)out_size; (void)ws_size;
    const float* q     = (const float*)d_in[0];
    const float* k     = (const float*)d_in[1];
    const float* v     = (const float*)d_in[2];
    const float* tau   = (const float*)d_in[3];
    const float* delta = (const float*)d_in[4];
    float* out = (float*)d_out;

    short* Kf = (short*)d_ws;                          // 8 MiB bf16 fragments
    short* Vf = (short*)d_ws + (size_t)(4*1024*1024);  // next 8 MiB

    prep_kv<<<dim3(Bsz*Hsz*32*2), dim3(256), 0, stream>>>(k, v, Kf, Vf);
    dsattn_main<<<dim3(Bsz*Hsz, 32), dim3(256), 0, stream>>>(q, Kf, Vf, tau, delta, out);
}